// Round 7
// baseline (352.029 us; speedup 1.0000x reference)
//
#include <hip/hip_runtime.h>

#define HDIM 1024
#define BDIM 32
#define LDIM 1024

// ws layout (floats): u1[0:H], u2[H:2H], vbar[2H : 2H+B*H], logits[2H+B*H : +B*L]

typedef float vfloat4 __attribute__((ext_vector_type(4)));

__device__ __forceinline__ float dot4(float4 a, float4 b) {
    return a.x * b.x + a.y * b.y + a.z * b.z + a.w * b.w;
}

__device__ __forceinline__ float4 ntload4(const float4* p) {
    vfloat4 v = __builtin_nontemporal_load((const vfloat4*)p);
    return make_float4(v.x, v.y, v.z, v.w);
}

// u1[h] = sum_o W[o,h]*w1[o]; u2[h] = sum_o W[o,h]*w2[o]. Coalesced row reads.
__global__ __launch_bounds__(256) void k_u12(const float4* __restrict__ W4,
                                             const float* __restrict__ mlp_w,
                                             float* __restrict__ u1,
                                             float* __restrict__ u2) {
    int t  = threadIdx.x;            // float4 index within a row, [0,256)
    int o0 = blockIdx.x * 16;        // 64 blocks x 16 rows
    float4 s1 = make_float4(0.f, 0.f, 0.f, 0.f);
    float4 s2 = make_float4(0.f, 0.f, 0.f, 0.f);
    #pragma unroll 4
    for (int o = o0; o < o0 + 16; ++o) {
        float4 w = W4[o * 256 + t];
        float c1 = mlp_w[o];
        float c2 = mlp_w[HDIM + o];
        s1.x += w.x * c1; s1.y += w.y * c1; s1.z += w.z * c1; s1.w += w.w * c1;
        s2.x += w.x * c2; s2.y += w.y * c2; s2.z += w.z * c2; s2.w += w.w * c2;
    }
    int h = t * 4;
    atomicAdd(&u1[h + 0], s1.x); atomicAdd(&u1[h + 1], s1.y);
    atomicAdd(&u1[h + 2], s1.z); atomicAdd(&u1[h + 3], s1.w);
    atomicAdd(&u2[h + 0], s2.x); atomicAdd(&u2[h + 1], s2.y);
    atomicAdd(&u2[h + 2], s2.z); atomicAdd(&u2[h + 3], s2.w);
}

// logits[row] = relu(q[row]·u1 + k[row]·u2 + b).
// Block owns 8 rows; thread owns float4 slice t of each row. 16 nontemporal
// loads in flight (8 q + 8 k) before any use. Cross-wave LDS combine
// (each wave's shuffle-reduce is a quarter dot).
__global__ __launch_bounds__(256) void k_logits(const float4* __restrict__ q,
                                                const float4* __restrict__ k,
                                                const float4* __restrict__ u1v,
                                                const float4* __restrict__ u2v,
                                                const float* __restrict__ mlp_b,
                                                float* __restrict__ logits) {
    __shared__ float sm[8][4];
    int t = threadIdx.x;
    int lane = t & 63, wave = t >> 6;
    float4 a1 = u1v[t];
    float4 a2 = u2v[t];
    float bias = mlp_b[0];
    long long r0 = (long long)blockIdx.x * 8;    // [0, 32768) step 8
    const float4* qb = q + r0 * 256 + t;
    const float4* kb = k + r0 * 256 + t;
    float4 xq[8], xk[8];
    #pragma unroll
    for (int r = 0; r < 8; ++r) xq[r] = ntload4(qb + r * 256);
    #pragma unroll
    for (int r = 0; r < 8; ++r) xk[r] = ntload4(kb + r * 256);
    float p[8];
    #pragma unroll
    for (int r = 0; r < 8; ++r)
        p[r] = dot4(xq[r], a1) + dot4(xk[r], a2);
    // 8 independent reduce chains, stage-major so they pipeline
    #pragma unroll
    for (int off = 32; off > 0; off >>= 1)
        #pragma unroll
        for (int r = 0; r < 8; ++r)
            p[r] += __shfl_down(p[r], off, 64);
    if (lane == 0) {
        #pragma unroll
        for (int r = 0; r < 8; ++r)
            sm[r][wave] = p[r];
    }
    __syncthreads();
    if (t < 8) {
        float v = sm[t][0] + sm[t][1] + sm[t][2] + sm[t][3] + bias;
        logits[r0 + t] = v > 0.f ? v : 0.f;
    }
}

__global__ __launch_bounds__(256) void k_softmax(const float* __restrict__ logits,
                                                 float* __restrict__ score) {
    __shared__ float sm[4];
    __shared__ float ss[4];
    int b = blockIdx.x;
    int t = threadIdx.x;
    int wave = t >> 6, lane = t & 63;
    float4 v = ((const float4*)(logits + b * LDIM))[t];
    float m = fmaxf(fmaxf(v.x, v.y), fmaxf(v.z, v.w));
    #pragma unroll
    for (int off = 32; off > 0; off >>= 1)
        m = fmaxf(m, __shfl_down(m, off, 64));
    if (lane == 0) sm[wave] = m;
    __syncthreads();
    float M = fmaxf(fmaxf(sm[0], sm[1]), fmaxf(sm[2], sm[3]));
    float4 e;
    e.x = __expf(v.x - M); e.y = __expf(v.y - M);
    e.z = __expf(v.z - M); e.w = __expf(v.w - M);
    float s = e.x + e.y + e.z + e.w;
    #pragma unroll
    for (int off = 32; off > 0; off >>= 1)
        s += __shfl_down(s, off, 64);
    if (lane == 0) ss[wave] = s;
    __syncthreads();
    float inv = 1.f / (ss[0] + ss[1] + ss[2] + ss[3]);
    float4 o;
    o.x = e.x * inv; o.y = e.y * inv; o.z = e.z * inv; o.w = e.w * inv;
    ((float4*)(score + b * LDIM))[t] = o;
}

// vbar[b,h] = sum_l score[b,l] * value[b,l,h].
// Grid 512: (b, 64-row l-chunk). CONTIGUOUS streaming: thread t owns h-slice
// [4t,4t+4) of every row; block reads 64 consecutive full rows (256 KB
// unbroken stream). Scores broadcast from LDS. One float4 acc; unique h-slice
// per thread in block -> no cross-wave reduce; 4 atomicAdds per thread
// (16 contender-blocks per address).
__global__ __launch_bounds__(256) void k_vbar(const float4* __restrict__ value,
                                              const float* __restrict__ score,
                                              float* __restrict__ vbar) {
    __shared__ float sc_lds[64];
    int b  = blockIdx.x >> 4;    // [0,32)
    int lc = blockIdx.x & 15;    // [0,16) chunks of 64 rows
    int t  = threadIdx.x;
    const float4* vb = value + ((long long)(b * LDIM + lc * 64) * 256) + t;
    if (t < 64) sc_lds[t] = score[b * LDIM + lc * 64 + t];
    __syncthreads();
    float4 acc = make_float4(0.f, 0.f, 0.f, 0.f);
    #pragma unroll 1
    for (int j = 0; j < 64; j += 8) {
        float4 v0 = ntload4(vb + (j + 0) * 256);
        float4 v1 = ntload4(vb + (j + 1) * 256);
        float4 v2 = ntload4(vb + (j + 2) * 256);
        float4 v3 = ntload4(vb + (j + 3) * 256);
        float4 v4 = ntload4(vb + (j + 4) * 256);
        float4 v5 = ntload4(vb + (j + 5) * 256);
        float4 v6 = ntload4(vb + (j + 6) * 256);
        float4 v7 = ntload4(vb + (j + 7) * 256);
        float s0 = sc_lds[j + 0], s1 = sc_lds[j + 1];
        float s2 = sc_lds[j + 2], s3 = sc_lds[j + 3];
        float s4 = sc_lds[j + 4], s5 = sc_lds[j + 5];
        float s6 = sc_lds[j + 6], s7 = sc_lds[j + 7];
        acc.x += s0 * v0.x + s1 * v1.x + s2 * v2.x + s3 * v3.x
               + s4 * v4.x + s5 * v5.x + s6 * v6.x + s7 * v7.x;
        acc.y += s0 * v0.y + s1 * v1.y + s2 * v2.y + s3 * v3.y
               + s4 * v4.y + s5 * v5.y + s6 * v6.y + s7 * v7.y;
        acc.z += s0 * v0.z + s1 * v1.z + s2 * v2.z + s3 * v3.z
               + s4 * v4.z + s5 * v5.z + s6 * v6.z + s7 * v7.z;
        acc.w += s0 * v0.w + s1 * v1.w + s2 * v2.w + s3 * v3.w
               + s4 * v4.w + s5 * v5.w + s6 * v6.w + s7 * v7.w;
    }
    float* dst = vbar + b * HDIM + t * 4;
    atomicAdd(dst + 0, acc.x);
    atomicAdd(dst + 1, acc.y);
    atomicAdd(dst + 2, acc.z);
    atomicAdd(dst + 3, acc.w);
}

// result[b,o] = sum_h W[o,h] * vbar[b,h]. One wave per o; b-range split 4-way.
__global__ __launch_bounds__(256) void k_result(const float4* __restrict__ W4,
                                                const float4* __restrict__ vbar4,
                                                float* __restrict__ result) {
    int t = threadIdx.x;
    int lane = t & 63, wave = t >> 6;
    int o  = (blockIdx.x & 255) * 4 + wave;   // [0,1024)
    int b0 = (blockIdx.x >> 8) * 8;           // {0,8,16,24}
    float4 w[4];
    #pragma unroll
    for (int i = 0; i < 4; ++i)
        w[i] = W4[o * 256 + lane + 64 * i];
    for (int b = b0; b < b0 + 8; b += 2) {
        float acc0 = 0.f, acc1 = 0.f;
        #pragma unroll
        for (int i = 0; i < 4; ++i) {
            float4 v0 = vbar4[b * 256 + lane + 64 * i];
            acc0 += v0.x * w[i].x + v0.y * w[i].y + v0.z * w[i].z + v0.w * w[i].w;
            float4 v1 = vbar4[(b + 1) * 256 + lane + 64 * i];
            acc1 += v1.x * w[i].x + v1.y * w[i].y + v1.z * w[i].z + v1.w * w[i].w;
        }
        #pragma unroll
        for (int off = 32; off > 0; off >>= 1) {
            acc0 += __shfl_down(acc0, off, 64);
            acc1 += __shfl_down(acc1, off, 64);
        }
        if (lane == 0) {
            result[b * HDIM + o]       = acc0;
            result[(b + 1) * HDIM + o] = acc1;
        }
    }
}

extern "C" void kernel_launch(void* const* d_in, const int* in_sizes, int n_in,
                              void* d_out, int out_size, void* d_ws, size_t ws_size,
                              hipStream_t stream) {
    const float* query = (const float*)d_in[0];
    const float* key   = (const float*)d_in[1];
    const float* value = (const float*)d_in[2];
    const float* W     = (const float*)d_in[3];
    const float* mlp_w = (const float*)d_in[4];
    const float* mlp_b = (const float*)d_in[5];

    float* out    = (float*)d_out;
    float* result = out;                 // B*H
    float* score  = out + BDIM * LDIM;   // B*L

    float* u1     = (float*)d_ws;
    float* u2     = u1 + HDIM;
    float* vbar   = u2 + HDIM;           // B*H
    float* logits = vbar + BDIM * HDIM;  // B*L

    hipMemsetAsync(d_ws, 0, (size_t)(2 * HDIM + BDIM * HDIM) * sizeof(float), stream);

    k_u12<<<64, 256, 0, stream>>>((const float4*)W, mlp_w, u1, u2);
    k_logits<<<4096, 256, 0, stream>>>((const float4*)query, (const float4*)key,
                                       (const float4*)u1, (const float4*)u2, mlp_b, logits);
    k_softmax<<<BDIM, 256, 0, stream>>>(logits, score);
    k_vbar<<<512, 256, 0, stream>>>((const float4*)value, score, vbar);
    k_result<<<1024, 256, 0, stream>>>((const float4*)W, (const float4*)vbar, out);
}